// Round 11
// baseline (338.370 us; speedup 1.0000x reference)
//
#include <hip/hip_runtime.h>
#include <math.h>

#define N_NODES 50000
#define N_EDGES 800000
#define D 64
#define N_GRAPHS 512
#define N_CLASSES 10
#define NPART 6250     // nodes per XCD partition (50000/8)
#define NB_L 782       // layer blocks: 64 nodes each (782*64 = 50048)

#define SCAN_B 512
#define NB_SCAN ((N_NODES + SCAN_B - 1) / SCAN_B)  // 98

typedef __attribute__((ext_vector_type(8))) short bf16x8;
typedef __attribute__((ext_vector_type(4))) float f32x4;

#define MFMA16(a, b, c) __builtin_amdgcn_mfma_f32_16x16x32_bf16(a, b, c, 0, 0, 0)

// ---------------- helpers ----------------

__device__ __forceinline__ unsigned mapf(float f) {
  unsigned u = __float_as_uint(f);
  return (u & 0x80000000u) ? ~u : (u | 0x80000000u);
}
__device__ __forceinline__ float unmapf(unsigned u) {
  return __uint_as_float((u & 0x80000000u) ? (u & 0x7FFFFFFFu) : ~u);
}
__device__ __forceinline__ ushort bf16_rne(float f) {
  unsigned u = __float_as_uint(f);
  u += 0x7FFFu + ((u >> 16) & 1u);
  return (ushort)(u >> 16);
}
__device__ __forceinline__ float bf16_tof(ushort h) {
  return __uint_as_float(((unsigned)h) << 16);
}
__device__ __forceinline__ unsigned pack2(float a, float b) {
  return (unsigned)bf16_rne(a) | ((unsigned)bf16_rne(b) << 16);
}
__device__ __forceinline__ float2 unpack2(unsigned v) {
  return make_float2(__uint_as_float(v << 16), __uint_as_float(v & 0xFFFF0000u));
}

// ---------------- weight fragment prep (hi/lo split) ----------------
// wf (ushorts): per layer 16384: W1hi@0, W1lo@4096, W2hi@8192, W2lo@12288.
// within region: frag f (8), lane (64), v (8): off = f*512 + lane*8 + v
// value = W[k][n], k = (f&1)*32 + (lane>>4)*8 + v, n = (f>>1)*16 + (lane&15)

__global__ void wprep(const float* __restrict__ convW1, const float* __restrict__ convW2,
                      ushort* __restrict__ wf) {
  const int wi = blockIdx.x;  // 0..5 = layer*2 + which
  const int layer = wi >> 1, which = wi & 1;
  const float* W = (which ? convW2 : convW1) + layer * 4096;
  const int t = threadIdx.x;  // 0..511
  const int f = t >> 6, lane = t & 63;
  const int ct = f >> 1, ks = f & 1;
  const int n = ct * 16 + (lane & 15);
  const int k0 = ks * 32 + ((lane >> 4) << 3);
  ushort hi[8], lo[8];
#pragma unroll
  for (int v = 0; v < 8; ++v) {
    float w = W[(k0 + v) * 64 + n];
    ushort h = bf16_rne(w);
    hi[v] = h;
    lo[v] = bf16_rne(w - bf16_tof(h));
  }
  ushort* base = wf + layer * 16384 + which * 8192;
  *(uint4*)(base + f * 512 + lane * 8) = *(uint4*)hi;
  *(uint4*)(base + 4096 + f * 512 + lane * 8) = *(uint4*)lo;
}

// ---------------- CSR build (XCD-partitioned writes) ----------------

__global__ void hist_part(const int* __restrict__ dst, int* __restrict__ deg) {
  const int p = blockIdx.x & 7;
  const int lo = p * NPART, hi = lo + NPART;
  const int stride = (gridDim.x >> 3) * 256;
  for (int e = (blockIdx.x >> 3) * 256 + threadIdx.x; e < N_EDGES; e += stride) {
    int d = dst[e];
    if (d >= lo && d < hi) atomicAdd(&deg[d], 1);
  }
}

__global__ void scan_blocks(const int* __restrict__ deg, int* __restrict__ bsum) {
  __shared__ int sd[SCAN_B];
  int i = blockIdx.x * SCAN_B + threadIdx.x;
  sd[threadIdx.x] = (i < N_NODES) ? deg[i] : 0;
  __syncthreads();
  for (int off = SCAN_B / 2; off > 0; off >>= 1) {
    if (threadIdx.x < off) sd[threadIdx.x] += sd[threadIdx.x + off];
    __syncthreads();
  }
  if (threadIdx.x == 0) bsum[blockIdx.x] = sd[0];
}

__global__ void scan_mid(int* __restrict__ bsum) {
  __shared__ int s[256];
  int t = threadIdx.x;
  if (t < NB_SCAN) s[t] = bsum[t];
  __syncthreads();
  if (t == 0) {
    int run = 0;
    for (int i = 0; i < NB_SCAN; ++i) { int v = s[i]; s[i] = run; run += v; }
  }
  __syncthreads();
  if (t < NB_SCAN) bsum[t] = s[t];
}

__global__ void scan_final(const int* __restrict__ deg, const int* __restrict__ bsum,
                           int* __restrict__ rs, int* __restrict__ cur) {
  __shared__ int sd[SCAN_B];
  int i = blockIdx.x * SCAN_B + threadIdx.x;
  int v = (i < N_NODES) ? deg[i] : 0;
  sd[threadIdx.x] = v;
  __syncthreads();
  for (int off = 1; off < SCAN_B; off <<= 1) {
    int add = (threadIdx.x >= off) ? sd[threadIdx.x - off] : 0;
    __syncthreads();
    sd[threadIdx.x] += add;
    __syncthreads();
  }
  if (i < N_NODES) {
    int ex = bsum[blockIdx.x] + sd[threadIdx.x] - v;
    rs[i] = ex;
    cur[i] = ex;
  }
  if (i == 0) rs[N_NODES] = N_EDGES;
}

__global__ void fill_part(const int* __restrict__ src, const int* __restrict__ dst,
                          int* __restrict__ cur, int* __restrict__ csr) {
  const int p = blockIdx.x & 7;
  const int lo = p * NPART, hi = lo + NPART;
  const int stride = (gridDim.x >> 3) * 256;
  for (int e = (blockIdx.x >> 3) * 256 + threadIdx.x; e < N_EDGES; e += stride) {
    int d = dst[e];
    if (d >= lo && d < hi) {
      int pos = atomicAdd(&cur[d], 1);
      csr[pos] = src[e];
    }
  }
}

// ---------------- fused GIN layer: gather + MLP (+ final pooling) ----------------
// Block: 256 threads, 64 nodes. Gather: half-wave hw owns nodes hw*8..hw*8+7
// (agg structure: 32 lanes/node, 2 feats/lane, f32 accumulate) -> bf16 rows in
// LDS tile At[64][72]. Wave w's own half-waves produce exactly the 16 rows wave w
// MFMAs, so only the weight-stage barrier is needed. At doubles as the GEMM1->GEMM2
// transpose buffer (A-frags are consumed first; same-wave LDS ordering).
// A-frag: lane row=lane&15, k=(ks*32)+(lane>>4)*8+v. C/D: col=lane&15, row=(lane>>4)*4+j.

template <int FINAL, int F32IN>
__global__ __launch_bounds__(256, 3) void gin_layer(
    const void* __restrict__ hin_, unsigned* __restrict__ hout,
    const int* __restrict__ csr, const int* __restrict__ rs,
    const ushort* __restrict__ wfL,   // layer base (16384 ushorts)
    const float* __restrict__ b1, const float* __restrict__ b2,
    const int* __restrict__ batch, unsigned* __restrict__ gU) {
  __shared__ ushort Wl[16384];    // 32KB: W1hi@0 W1lo@8192B W2hi@16384B W2lo@24576B
  __shared__ ushort At[64][72];   // 9KB gather tile / transpose buffer
  const int t = threadIdx.x;
  const int w = t >> 6, lane = t & 63;
  const int m = lane & 15, g = lane >> 4;
  const int base = blockIdx.x * 64;

  // ---- stage all weights (32KB) ----
  {
    const uint4* s = (const uint4*)wfL;
    uint4* d = (uint4*)Wl;
#pragma unroll
    for (int i = 0; i < 8; ++i) d[t + 256 * i] = s[t + 256 * i];
  }

  // ---- gather: half-wave hw -> 8 nodes, f32 accumulate, bf16 into At ----
  {
    const int hw = t >> 5, hl = t & 31;
    const float* hf = (const float*)hin_;
    const unsigned* hb = (const unsigned*)hin_;
    for (int i = 0; i < 8; ++i) {
      const int nl = hw * 8 + i;
      const int node = base + nl;
      float2 a = make_float2(0.f, 0.f);
      if (node < N_NODES) {
        if (F32IN) a = ((const float2*)(hf + (size_t)node * 64))[hl];
        else       a = unpack2(hb[node * 32 + hl]);
        int e = rs[node];
        const int e1 = rs[node + 1];
        if (F32IN) {
          for (; e + 4 <= e1; e += 4) {
            int s0 = csr[e], s1 = csr[e + 1], s2 = csr[e + 2], s3 = csr[e + 3];
            float2 v0 = ((const float2*)(hf + (size_t)s0 * 64))[hl];
            float2 v1 = ((const float2*)(hf + (size_t)s1 * 64))[hl];
            float2 v2 = ((const float2*)(hf + (size_t)s2 * 64))[hl];
            float2 v3 = ((const float2*)(hf + (size_t)s3 * 64))[hl];
            a.x += v0.x + v1.x; a.y += v0.y + v1.y;
            a.x += v2.x + v3.x; a.y += v2.y + v3.y;
          }
          for (; e < e1; ++e) {
            float2 v = ((const float2*)(hf + (size_t)csr[e] * 64))[hl];
            a.x += v.x; a.y += v.y;
          }
        } else {
          for (; e + 4 <= e1; e += 4) {
            int s0 = csr[e], s1 = csr[e + 1], s2 = csr[e + 2], s3 = csr[e + 3];
            float2 v0 = unpack2(hb[s0 * 32 + hl]);
            float2 v1 = unpack2(hb[s1 * 32 + hl]);
            float2 v2 = unpack2(hb[s2 * 32 + hl]);
            float2 v3 = unpack2(hb[s3 * 32 + hl]);
            a.x += v0.x + v1.x; a.y += v0.y + v1.y;
            a.x += v2.x + v3.x; a.y += v2.y + v3.y;
          }
          for (; e < e1; ++e) {
            float2 v = unpack2(hb[csr[e] * 32 + hl]);
            a.x += v.x; a.y += v.y;
          }
        }
      }
      *(unsigned*)&At[nl][2 * hl] = pack2(a.x, a.y);
    }
  }
  __syncthreads();  // weights + gather tile ready

  // ---- MLP: wave w -> tile rows [w*16, w*16+16) ----
  bf16x8 a0 = *(const bf16x8*)&At[w * 16 + m][g * 8];
  bf16x8 a1 = *(const bf16x8*)&At[w * 16 + m][32 + g * 8];
  const char* wb = (const char*)Wl + lane * 16;
  ushort* tw = &At[w * 16][0];
#define LDW(off) (*(const bf16x8*)(wb + (off)))

  // GEMM1: c = A@(W1hi + W1lo)
  f32x4 c0 = {0.f, 0.f, 0.f, 0.f}, c1 = c0, c2 = c0, c3 = c0;
#define G1(ct, cc)                                      \
  cc = MFMA16(a0, LDW((2 * ct + 0) * 1024), cc);        \
  cc = MFMA16(a1, LDW((2 * ct + 1) * 1024), cc);        \
  cc = MFMA16(a0, LDW(8192 + (2 * ct + 0) * 1024), cc); \
  cc = MFMA16(a1, LDW(8192 + (2 * ct + 1) * 1024), cc);
  G1(0, c0) G1(1, c1) G1(2, c2) G1(3, c3)
#undef G1

  // bias + relu -> bf16 transpose (reuse At rows of this wave)
  {
    float bv0 = b1[m], bv1 = b1[16 + m], bv2 = b1[32 + m], bv3 = b1[48 + m];
#define WRT(cc, ct, bv)                                                    \
    tw[(g * 4 + 0) * 72 + ct * 16 + m] = bf16_rne(fmaxf(cc[0] + bv, 0.f)); \
    tw[(g * 4 + 1) * 72 + ct * 16 + m] = bf16_rne(fmaxf(cc[1] + bv, 0.f)); \
    tw[(g * 4 + 2) * 72 + ct * 16 + m] = bf16_rne(fmaxf(cc[2] + bv, 0.f)); \
    tw[(g * 4 + 3) * 72 + ct * 16 + m] = bf16_rne(fmaxf(cc[3] + bv, 0.f));
    WRT(c0, 0, bv0) WRT(c1, 1, bv1) WRT(c2, 2, bv2) WRT(c3, 3, bv3)
#undef WRT
  }
  bf16x8 h0 = *(const bf16x8*)(tw + m * 72 + g * 8);
  bf16x8 h1 = *(const bf16x8*)(tw + m * 72 + 32 + g * 8);

  // GEMM2: c = H@(W2hi + W2lo)
  c0 = (f32x4){0.f, 0.f, 0.f, 0.f}; c1 = c0; c2 = c0; c3 = c0;
#define G2(ct, cc)                                       \
  cc = MFMA16(h0, LDW(16384 + (2 * ct + 0) * 1024), cc); \
  cc = MFMA16(h1, LDW(16384 + (2 * ct + 1) * 1024), cc); \
  cc = MFMA16(h0, LDW(24576 + (2 * ct + 0) * 1024), cc); \
  cc = MFMA16(h1, LDW(24576 + (2 * ct + 1) * 1024), cc);
  G2(0, c0) G2(1, c1) G2(2, c2) G2(3, c3)
#undef G2
#undef LDW

  const float bv20 = b2[m], bv21 = b2[16 + m], bv22 = b2[32 + m], bv23 = b2[48 + m];
  if (FINAL) {
    const int tb = base + w * 16;
#define PM(cc, ct, bv, j)                                             \
    { int node = tb + g * 4 + j;                                      \
      if (node < N_NODES)                                             \
        atomicMax(&gU[batch[node] * 64 + ct * 16 + m], mapf(cc[j] + bv)); }
#define PM4(cc, ct, bv) PM(cc, ct, bv, 0) PM(cc, ct, bv, 1) PM(cc, ct, bv, 2) PM(cc, ct, bv, 3)
    PM4(c0, 0, bv20) PM4(c1, 1, bv21) PM4(c2, 2, bv22) PM4(c3, 3, bv23)
#undef PM4
#undef PM
  } else {
    // bias -> bf16 back into tw, then coalesced stores (lane l owns 32B chunk l)
#define WRO(cc, ct, bv)                                        \
    tw[(g * 4 + 0) * 72 + ct * 16 + m] = bf16_rne(cc[0] + bv); \
    tw[(g * 4 + 1) * 72 + ct * 16 + m] = bf16_rne(cc[1] + bv); \
    tw[(g * 4 + 2) * 72 + ct * 16 + m] = bf16_rne(cc[2] + bv); \
    tw[(g * 4 + 3) * 72 + ct * 16 + m] = bf16_rne(cc[3] + bv);
    WRO(c0, 0, bv20) WRO(c1, 1, bv21) WRO(c2, 2, bv22) WRO(c3, 3, bv23)
#undef WRO
    const int r = lane >> 2, q = lane & 3;
    if (base + w * 16 + r < N_NODES) {
      uint4 v0 = *(const uint4*)(tw + r * 72 + q * 16);
      uint4 v1 = *(const uint4*)(tw + r * 72 + q * 16 + 8);
      ushort* Ao = (ushort*)hout + (size_t)(base + w * 16) * 64;
      *(uint4*)(Ao + lane * 16) = v0;
      *(uint4*)(Ao + lane * 16 + 8) = v1;
    }
  }
}

// ---------------- pooling init + head ----------------

__global__ void init_g(unsigned* __restrict__ gU) {
  int i = blockIdx.x * blockDim.x + threadIdx.x;
  if (i < N_GRAPHS * D) gU[i] = 0x007FFFFFu;  // mapf(-inf)
}

__global__ void head_kernel(const unsigned* __restrict__ gU,
                            const float* __restrict__ fcW1, const float* __restrict__ fcb1,
                            const float* __restrict__ fcW2, const float* __restrict__ fcb2,
                            float* __restrict__ out) {
  __shared__ float gbuf[64];
  __shared__ float hid[64];
  __shared__ float logit[N_CLASSES];
  __shared__ float red[2];
  const int gi = blockIdx.x;
  const int t = threadIdx.x;

  gbuf[t] = unmapf(gU[gi * D + t]);
  __syncthreads();

  float a = fcb1[t];
#pragma unroll
  for (int k = 0; k < 64; ++k) a = fmaf(gbuf[k], fcW1[k * 64 + t], a);
  hid[t] = fmaxf(a, 0.0f);
  __syncthreads();

  if (t < N_CLASSES) {
    float l = fcb2[t];
#pragma unroll
    for (int k = 0; k < 64; ++k) l = fmaf(hid[k], fcW2[k * N_CLASSES + t], l);
    logit[t] = l;
  }
  __syncthreads();

  if (t == 0) {
    float mx = logit[0];
    for (int i = 1; i < N_CLASSES; ++i) mx = fmaxf(mx, logit[i]);
    float s = 0.0f;
    for (int i = 0; i < N_CLASSES; ++i) s += expf(logit[i] - mx);
    red[0] = mx;
    red[1] = logf(s);
  }
  __syncthreads();

  if (t < N_CLASSES) out[gi * N_CLASSES + t] = logit[t] - red[0] - red[1];
}

// ---------------- launch ----------------

extern "C" void kernel_launch(void* const* d_in, const int* in_sizes, int n_in,
                              void* d_out, int out_size, void* d_ws, size_t ws_size,
                              hipStream_t stream) {
  const float* x      = (const float*)d_in[0];
  const float* convW1 = (const float*)d_in[1];
  const float* convb1 = (const float*)d_in[2];
  const float* convW2 = (const float*)d_in[3];
  const float* convb2 = (const float*)d_in[4];
  const float* fcW1   = (const float*)d_in[5];
  const float* fcb1   = (const float*)d_in[6];
  const float* fcW2   = (const float*)d_in[7];
  const float* fcb2   = (const float*)d_in[8];
  const int*   edge   = (const int*)d_in[9];
  const int*   batch  = (const int*)d_in[10];
  float* out = (float*)d_out;

  const int* src = edge;
  const int* dst = edge + N_EDGES;

  // workspace layout (~16.5 MB)
  unsigned* hbA = (unsigned*)d_ws;                  // 6.4 MB bf16 h1
  unsigned* hbB = hbA + (size_t)N_NODES * 32;       // 6.4 MB bf16 h2
  unsigned* gU  = hbB + (size_t)N_NODES * 32;       // 131 KB
  int* rs  = (int*)(gU + N_GRAPHS * D);             // 200 KB
  int* csr = rs + N_NODES + 1;                      // 3.2 MB
  ushort* wf = (ushort*)(csr + N_EDGES);            // 96 KB
  // deg/cur/bsum overlap hbA (dead before layer-1 writes hbA)
  int* deg  = (int*)hbA;
  int* cur  = deg + N_NODES;
  int* bsum = cur + N_NODES;

  // ---- prep ----
  wprep<<<6, 512, 0, stream>>>(convW1, convW2, wf);
  init_g<<<(N_GRAPHS * D + 255) / 256, 256, 0, stream>>>(gU);

  // ---- CSR build (dst-indexed, XCD-partitioned writes) ----
  hipMemsetAsync(deg, 0, N_NODES * sizeof(int), stream);
  hist_part<<<2048, 256, 0, stream>>>(dst, deg);
  scan_blocks<<<NB_SCAN, SCAN_B, 0, stream>>>(deg, bsum);
  scan_mid<<<1, 256, 0, stream>>>(bsum);
  scan_final<<<NB_SCAN, SCAN_B, 0, stream>>>(deg, bsum, rs, cur);
  fill_part<<<2048, 256, 0, stream>>>(src, dst, cur, csr);

  // ---- 3 fused GIN layers ----
  gin_layer<0, 1><<<NB_L, 256, 0, stream>>>(x, hbA, csr, rs, wf,
                                            convb1, convb2, batch, gU);
  gin_layer<0, 0><<<NB_L, 256, 0, stream>>>(hbA, hbB, csr, rs, wf + 16384,
                                            convb1 + 64, convb2 + 64, batch, gU);
  gin_layer<1, 0><<<NB_L, 256, 0, stream>>>(hbB, nullptr, csr, rs, wf + 32768,
                                            convb1 + 128, convb2 + 128, batch, gU);

  // ---- FC head + log_softmax ----
  head_kernel<<<N_GRAPHS, 64, 0, stream>>>(gU, fcW1, fcb1, fcW2, fcb2, out);
}

// Round 12
// 229.402 us; speedup vs baseline: 1.4750x; 1.4750x over previous
//
#include <hip/hip_runtime.h>
#include <math.h>

#define N_NODES 50000
#define N_EDGES 800000
#define D 64
#define N_GRAPHS 512
#define N_CLASSES 10
#define NT 3125        // 16-row tiles
#define NB32 1563      // 32-node blocks (1563*32 >= 50000)
#define NPART 6250     // nodes per XCD partition (50000/8)

#define SCAN_B 512
#define NB_SCAN ((N_NODES + SCAN_B - 1) / SCAN_B)  // 98

typedef __attribute__((ext_vector_type(8))) short bf16x8;
typedef __attribute__((ext_vector_type(4))) float f32x4;

#define MFMA16(a, b, c) __builtin_amdgcn_mfma_f32_16x16x32_bf16(a, b, c, 0, 0, 0)

// ---------------- helpers ----------------

__device__ __forceinline__ unsigned mapf(float f) {
  unsigned u = __float_as_uint(f);
  return (u & 0x80000000u) ? ~u : (u | 0x80000000u);
}
__device__ __forceinline__ float unmapf(unsigned u) {
  return __uint_as_float((u & 0x80000000u) ? (u & 0x7FFFFFFFu) : ~u);
}
__device__ __forceinline__ ushort bf16_rne(float f) {
  unsigned u = __float_as_uint(f);
  u += 0x7FFFu + ((u >> 16) & 1u);
  return (ushort)(u >> 16);
}
__device__ __forceinline__ float bf16_tof(ushort h) {
  return __uint_as_float(((unsigned)h) << 16);
}
__device__ __forceinline__ unsigned pack2(float a, float b) {
  return (unsigned)bf16_rne(a) | ((unsigned)bf16_rne(b) << 16);
}
__device__ __forceinline__ float2 unpack2(unsigned v) {
  return make_float2(__uint_as_float(v << 16), __uint_as_float(v & 0xFFFF0000u));
}

// ---------------- weight fragment prep (hi/lo split) ----------------
// wf (ushorts): per layer 16384: W1hi@0, W1lo@4096, W2hi@8192, W2lo@12288.
// within region: frag f (8), lane (64), v (8): off = f*512 + lane*8 + v
// value = W[k][n], k = (f&1)*32 + (lane>>4)*8 + v, n = (f>>1)*16 + (lane&15)

__global__ void wprep(const float* __restrict__ convW1, const float* __restrict__ convW2,
                      ushort* __restrict__ wf) {
  const int wi = blockIdx.x;  // 0..5 = layer*2 + which
  const int layer = wi >> 1, which = wi & 1;
  const float* W = (which ? convW2 : convW1) + layer * 4096;
  const int t = threadIdx.x;  // 0..511
  const int f = t >> 6, lane = t & 63;
  const int ct = f >> 1, ks = f & 1;
  const int n = ct * 16 + (lane & 15);
  const int k0 = ks * 32 + ((lane >> 4) << 3);
  ushort hi[8], lo[8];
#pragma unroll
  for (int v = 0; v < 8; ++v) {
    float w = W[(k0 + v) * 64 + n];
    ushort h = bf16_rne(w);
    hi[v] = h;
    lo[v] = bf16_rne(w - bf16_tof(h));
  }
  ushort* base = wf + layer * 16384 + which * 8192;
  *(uint4*)(base + f * 512 + lane * 8) = *(uint4*)hi;
  *(uint4*)(base + 4096 + f * 512 + lane * 8) = *(uint4*)lo;
}

// ---------------- CSR build (XCD-partitioned writes) ----------------

__global__ void hist_part(const int* __restrict__ dst, int* __restrict__ deg) {
  const int p = blockIdx.x & 7;
  const int lo = p * NPART, hi = lo + NPART;
  const int stride = (gridDim.x >> 3) * 256;
  for (int e = (blockIdx.x >> 3) * 256 + threadIdx.x; e < N_EDGES; e += stride) {
    int d = dst[e];
    if (d >= lo && d < hi) atomicAdd(&deg[d], 1);
  }
}

__global__ void scan_blocks(const int* __restrict__ deg, int* __restrict__ bsum) {
  __shared__ int sd[SCAN_B];
  int i = blockIdx.x * SCAN_B + threadIdx.x;
  sd[threadIdx.x] = (i < N_NODES) ? deg[i] : 0;
  __syncthreads();
  for (int off = SCAN_B / 2; off > 0; off >>= 1) {
    if (threadIdx.x < off) sd[threadIdx.x] += sd[threadIdx.x + off];
    __syncthreads();
  }
  if (threadIdx.x == 0) bsum[blockIdx.x] = sd[0];
}

__global__ void scan_mid(int* __restrict__ bsum) {
  __shared__ int s[256];
  int t = threadIdx.x;
  if (t < NB_SCAN) s[t] = bsum[t];
  __syncthreads();
  if (t == 0) {
    int run = 0;
    for (int i = 0; i < NB_SCAN; ++i) { int v = s[i]; s[i] = run; run += v; }
  }
  __syncthreads();
  if (t < NB_SCAN) bsum[t] = s[t];
}

__global__ void scan_final(const int* __restrict__ deg, const int* __restrict__ bsum,
                           int* __restrict__ rs, int* __restrict__ cur) {
  __shared__ int sd[SCAN_B];
  int i = blockIdx.x * SCAN_B + threadIdx.x;
  int v = (i < N_NODES) ? deg[i] : 0;
  sd[threadIdx.x] = v;
  __syncthreads();
  for (int off = 1; off < SCAN_B; off <<= 1) {
    int add = (threadIdx.x >= off) ? sd[threadIdx.x - off] : 0;
    __syncthreads();
    sd[threadIdx.x] += add;
    __syncthreads();
  }
  if (i < N_NODES) {
    int ex = bsum[blockIdx.x] + sd[threadIdx.x] - v;
    rs[i] = ex;
    cur[i] = ex;
  }
  if (i == 0) rs[N_NODES] = N_EDGES;
}

__global__ void fill_part(const int* __restrict__ src, const int* __restrict__ dst,
                          int* __restrict__ cur, int* __restrict__ csr) {
  const int p = blockIdx.x & 7;
  const int lo = p * NPART, hi = lo + NPART;
  const int stride = (gridDim.x >> 3) * 256;
  for (int e = (blockIdx.x >> 3) * 256 + threadIdx.x; e < N_EDGES; e += stride) {
    int d = dst[e];
    if (d >= lo && d < hi) {
      int pos = atomicAdd(&cur[d], 1);
      csr[pos] = src[e];
    }
  }
}

// ---------------- fused GIN layer, high-TLP gather variant ----------------
// Block: 256 threads, 32 nodes. Gather: quarter-wave qw (16 lanes, 8B/lane for
// bf16 rows, 16B/lane for f32 rows) owns nodes qw and qw+16 — serial depth 2,
// ~16k resident chains at 4 blocks/CU. Results -> LDS At[32][72] (bf16).
// MLP: waves 0,1 each MFMA one 16-row tile (w-frags from LDS, transpose in At);
// waves 2,3 exit. Only the gather touches fresh global data (high TLP hides it).
// A-frag: lane row=lane&15, k=(ks*32)+(lane>>4)*8+v. C/D: col=lane&15, row=(lane>>4)*4+j.

template <int FINAL, int F32IN>
__global__ __launch_bounds__(256, 4) void gin32(
    const void* __restrict__ hin_, unsigned* __restrict__ hout,
    const int* __restrict__ csr, const int* __restrict__ rs,
    const ushort* __restrict__ wfL,   // layer base (16384 ushorts)
    const float* __restrict__ b1, const float* __restrict__ b2,
    const int* __restrict__ batch, unsigned* __restrict__ gU) {
  __shared__ ushort Wl[16384];    // 32KB: W1hi@0 W1lo@8192B W2hi@16384B W2lo@24576B
  __shared__ ushort At[32][72];   // 4.5KB gather tile / transpose buffer
  const int t = threadIdx.x;

  // ---- stage all weights (32KB) ----
  {
    const uint4* s = (const uint4*)wfL;
    uint4* d = (uint4*)Wl;
#pragma unroll
    for (int i = 0; i < 8; ++i) d[t + 256 * i] = s[t + 256 * i];
  }

  // ---- gather: quarter-wave qw -> nodes qw, qw+16 (f32 accumulate) ----
  {
    const int qw = t >> 4, ql = t & 15;
    const float4* hf = (const float4*)hin_;  // f32 row = 16 float4
    const uint2* hb = (const uint2*)hin_;    // bf16 row = 16 uint2
#pragma unroll
    for (int i = 0; i < 2; ++i) {
      const int nl = qw + 16 * i;
      const int node = blockIdx.x * 32 + nl;
      float ax = 0.f, ay = 0.f, az = 0.f, aw = 0.f;
      if (node < N_NODES) {
        if (F32IN) {
          float4 v = hf[node * 16 + ql];
          ax = v.x; ay = v.y; az = v.z; aw = v.w;
        } else {
          uint2 u = hb[node * 16 + ql];
          float2 p0 = unpack2(u.x), p1 = unpack2(u.y);
          ax = p0.x; ay = p0.y; az = p1.x; aw = p1.y;
        }
        int e = rs[node];
        const int e1 = rs[node + 1];
        if (F32IN) {
          for (; e + 4 <= e1; e += 4) {
            int s0 = csr[e], s1 = csr[e + 1], s2 = csr[e + 2], s3 = csr[e + 3];
            float4 v0 = hf[s0 * 16 + ql];
            float4 v1 = hf[s1 * 16 + ql];
            float4 v2 = hf[s2 * 16 + ql];
            float4 v3 = hf[s3 * 16 + ql];
            ax += v0.x + v1.x; ay += v0.y + v1.y; az += v0.z + v1.z; aw += v0.w + v1.w;
            ax += v2.x + v3.x; ay += v2.y + v3.y; az += v2.z + v3.z; aw += v2.w + v3.w;
          }
          for (; e < e1; ++e) {
            float4 v = hf[csr[e] * 16 + ql];
            ax += v.x; ay += v.y; az += v.z; aw += v.w;
          }
        } else {
          for (; e + 4 <= e1; e += 4) {
            int s0 = csr[e], s1 = csr[e + 1], s2 = csr[e + 2], s3 = csr[e + 3];
            uint2 u0 = hb[s0 * 16 + ql];
            uint2 u1 = hb[s1 * 16 + ql];
            uint2 u2 = hb[s2 * 16 + ql];
            uint2 u3 = hb[s3 * 16 + ql];
            float2 q0, q1;
            q0 = unpack2(u0.x); q1 = unpack2(u0.y); ax += q0.x; ay += q0.y; az += q1.x; aw += q1.y;
            q0 = unpack2(u1.x); q1 = unpack2(u1.y); ax += q0.x; ay += q0.y; az += q1.x; aw += q1.y;
            q0 = unpack2(u2.x); q1 = unpack2(u2.y); ax += q0.x; ay += q0.y; az += q1.x; aw += q1.y;
            q0 = unpack2(u3.x); q1 = unpack2(u3.y); ax += q0.x; ay += q0.y; az += q1.x; aw += q1.y;
          }
          for (; e < e1; ++e) {
            uint2 u = hb[csr[e] * 16 + ql];
            float2 q0 = unpack2(u.x), q1 = unpack2(u.y);
            ax += q0.x; ay += q0.y; az += q1.x; aw += q1.y;
          }
        }
      }
      *(uint2*)&At[nl][4 * ql] = make_uint2(pack2(ax, ay), pack2(az, aw));
    }
  }
  __syncthreads();  // weights + gather tile ready

  // ---- MLP: waves 0,1 -> tiles; waves 2,3 done ----
  const int w = t >> 6, lane = t & 63;
  if (w >= 2) return;
  const int tile = blockIdx.x * 2 + w;
  if (tile >= NT) return;
  const int m = lane & 15, g = lane >> 4;
  ushort* tw = &At[w * 16][0];

  bf16x8 a0 = *(const bf16x8*)&At[w * 16 + m][g * 8];
  bf16x8 a1 = *(const bf16x8*)&At[w * 16 + m][32 + g * 8];
  const char* wb = (const char*)Wl + lane * 16;
#define LDW(off) (*(const bf16x8*)(wb + (off)))

  // GEMM1: c = A@(W1hi + W1lo)
  f32x4 c0 = {0.f, 0.f, 0.f, 0.f}, c1 = c0, c2 = c0, c3 = c0;
#define G1(ct, cc)                                      \
  cc = MFMA16(a0, LDW((2 * ct + 0) * 1024), cc);        \
  cc = MFMA16(a1, LDW((2 * ct + 1) * 1024), cc);        \
  cc = MFMA16(a0, LDW(8192 + (2 * ct + 0) * 1024), cc); \
  cc = MFMA16(a1, LDW(8192 + (2 * ct + 1) * 1024), cc);
  G1(0, c0) G1(1, c1) G1(2, c2) G1(3, c3)
#undef G1

  // bias + relu -> bf16 transpose (reuse this wave's At rows)
  {
    float bv0 = b1[m], bv1 = b1[16 + m], bv2 = b1[32 + m], bv3 = b1[48 + m];
#define WRT(cc, ct, bv)                                                    \
    tw[(g * 4 + 0) * 72 + ct * 16 + m] = bf16_rne(fmaxf(cc[0] + bv, 0.f)); \
    tw[(g * 4 + 1) * 72 + ct * 16 + m] = bf16_rne(fmaxf(cc[1] + bv, 0.f)); \
    tw[(g * 4 + 2) * 72 + ct * 16 + m] = bf16_rne(fmaxf(cc[2] + bv, 0.f)); \
    tw[(g * 4 + 3) * 72 + ct * 16 + m] = bf16_rne(fmaxf(cc[3] + bv, 0.f));
    WRT(c0, 0, bv0) WRT(c1, 1, bv1) WRT(c2, 2, bv2) WRT(c3, 3, bv3)
#undef WRT
  }
  bf16x8 h0 = *(const bf16x8*)(tw + m * 72 + g * 8);
  bf16x8 h1 = *(const bf16x8*)(tw + m * 72 + 32 + g * 8);

  // GEMM2: c = H@(W2hi + W2lo)
  c0 = (f32x4){0.f, 0.f, 0.f, 0.f}; c1 = c0; c2 = c0; c3 = c0;
#define G2(ct, cc)                                       \
  cc = MFMA16(h0, LDW(16384 + (2 * ct + 0) * 1024), cc); \
  cc = MFMA16(h1, LDW(16384 + (2 * ct + 1) * 1024), cc); \
  cc = MFMA16(h0, LDW(24576 + (2 * ct + 0) * 1024), cc); \
  cc = MFMA16(h1, LDW(24576 + (2 * ct + 1) * 1024), cc);
  G2(0, c0) G2(1, c1) G2(2, c2) G2(3, c3)
#undef G2
#undef LDW

  const float bv20 = b2[m], bv21 = b2[16 + m], bv22 = b2[32 + m], bv23 = b2[48 + m];
  if (FINAL) {
    const int tb = tile * 16;
#define PM(cc, ct, bv, j)                                           \
    atomicMax(&gU[batch[tb + g * 4 + j] * 64 + ct * 16 + m], mapf(cc[j] + bv));
#define PM4(cc, ct, bv) PM(cc, ct, bv, 0) PM(cc, ct, bv, 1) PM(cc, ct, bv, 2) PM(cc, ct, bv, 3)
    PM4(c0, 0, bv20) PM4(c1, 1, bv21) PM4(c2, 2, bv22) PM4(c3, 3, bv23)
#undef PM4
#undef PM
  } else {
    // bias -> bf16 back into tw, then coalesced stores (lane l owns 32B chunk l)
#define WRO(cc, ct, bv)                                        \
    tw[(g * 4 + 0) * 72 + ct * 16 + m] = bf16_rne(cc[0] + bv); \
    tw[(g * 4 + 1) * 72 + ct * 16 + m] = bf16_rne(cc[1] + bv); \
    tw[(g * 4 + 2) * 72 + ct * 16 + m] = bf16_rne(cc[2] + bv); \
    tw[(g * 4 + 3) * 72 + ct * 16 + m] = bf16_rne(cc[3] + bv);
    WRO(c0, 0, bv20) WRO(c1, 1, bv21) WRO(c2, 2, bv22) WRO(c3, 3, bv23)
#undef WRO
    const int r = lane >> 2, q = lane & 3;
    uint4 v0 = *(const uint4*)(tw + r * 72 + q * 16);
    uint4 v1 = *(const uint4*)(tw + r * 72 + q * 16 + 8);
    ushort* Ao = (ushort*)hout + (size_t)tile * 1024;
    *(uint4*)(Ao + lane * 16) = v0;
    *(uint4*)(Ao + lane * 16 + 8) = v1;
  }
}

// ---------------- pooling init + head ----------------

__global__ void init_g(unsigned* __restrict__ gU) {
  int i = blockIdx.x * blockDim.x + threadIdx.x;
  if (i < N_GRAPHS * D) gU[i] = 0x007FFFFFu;  // mapf(-inf)
}

__global__ void head_kernel(const unsigned* __restrict__ gU,
                            const float* __restrict__ fcW1, const float* __restrict__ fcb1,
                            const float* __restrict__ fcW2, const float* __restrict__ fcb2,
                            float* __restrict__ out) {
  __shared__ float gbuf[64];
  __shared__ float hid[64];
  __shared__ float logit[N_CLASSES];
  __shared__ float red[2];
  const int gi = blockIdx.x;
  const int t = threadIdx.x;

  gbuf[t] = unmapf(gU[gi * D + t]);
  __syncthreads();

  float a = fcb1[t];
#pragma unroll
  for (int k = 0; k < 64; ++k) a = fmaf(gbuf[k], fcW1[k * 64 + t], a);
  hid[t] = fmaxf(a, 0.0f);
  __syncthreads();

  if (t < N_CLASSES) {
    float l = fcb2[t];
#pragma unroll
    for (int k = 0; k < 64; ++k) l = fmaf(hid[k], fcW2[k * N_CLASSES + t], l);
    logit[t] = l;
  }
  __syncthreads();

  if (t == 0) {
    float mx = logit[0];
    for (int i = 1; i < N_CLASSES; ++i) mx = fmaxf(mx, logit[i]);
    float s = 0.0f;
    for (int i = 0; i < N_CLASSES; ++i) s += expf(logit[i] - mx);
    red[0] = mx;
    red[1] = logf(s);
  }
  __syncthreads();

  if (t < N_CLASSES) out[gi * N_CLASSES + t] = logit[t] - red[0] - red[1];
}

// ---------------- launch ----------------

extern "C" void kernel_launch(void* const* d_in, const int* in_sizes, int n_in,
                              void* d_out, int out_size, void* d_ws, size_t ws_size,
                              hipStream_t stream) {
  const float* x      = (const float*)d_in[0];
  const float* convW1 = (const float*)d_in[1];
  const float* convb1 = (const float*)d_in[2];
  const float* convW2 = (const float*)d_in[3];
  const float* convb2 = (const float*)d_in[4];
  const float* fcW1   = (const float*)d_in[5];
  const float* fcb1   = (const float*)d_in[6];
  const float* fcW2   = (const float*)d_in[7];
  const float* fcb2   = (const float*)d_in[8];
  const int*   edge   = (const int*)d_in[9];
  const int*   batch  = (const int*)d_in[10];
  float* out = (float*)d_out;

  const int* src = edge;
  const int* dst = edge + N_EDGES;

  // workspace layout (~16.5 MB)
  unsigned* hbA = (unsigned*)d_ws;                  // 6.4 MB bf16 h1
  unsigned* hbB = hbA + (size_t)N_NODES * 32;       // 6.4 MB bf16 h2
  unsigned* gU  = hbB + (size_t)N_NODES * 32;       // 131 KB
  int* rs  = (int*)(gU + N_GRAPHS * D);             // 200 KB
  int* csr = rs + N_NODES + 1;                      // 3.2 MB
  ushort* wf = (ushort*)(csr + N_EDGES);            // 96 KB
  // deg/cur/bsum overlap hbA (dead before layer-1 writes hbA)
  int* deg  = (int*)hbA;
  int* cur  = deg + N_NODES;
  int* bsum = cur + N_NODES;

  // ---- prep ----
  wprep<<<6, 512, 0, stream>>>(convW1, convW2, wf);
  init_g<<<(N_GRAPHS * D + 255) / 256, 256, 0, stream>>>(gU);

  // ---- CSR build (dst-indexed, XCD-partitioned writes) ----
  hipMemsetAsync(deg, 0, N_NODES * sizeof(int), stream);
  hist_part<<<2048, 256, 0, stream>>>(dst, deg);
  scan_blocks<<<NB_SCAN, SCAN_B, 0, stream>>>(deg, bsum);
  scan_mid<<<1, 256, 0, stream>>>(bsum);
  scan_final<<<NB_SCAN, SCAN_B, 0, stream>>>(deg, bsum, rs, cur);
  fill_part<<<2048, 256, 0, stream>>>(src, dst, cur, csr);

  // ---- 3 fused GIN layers ----
  gin32<0, 1><<<NB32, 256, 0, stream>>>(x, hbA, csr, rs, wf,
                                        convb1, convb2, batch, gU);
  gin32<0, 0><<<NB32, 256, 0, stream>>>(hbA, hbB, csr, rs, wf + 16384,
                                        convb1 + 64, convb2 + 64, batch, gU);
  gin32<1, 0><<<NB32, 256, 0, stream>>>(hbB, nullptr, csr, rs, wf + 32768,
                                        convb1 + 128, convb2 + 128, batch, gU);

  // ---- FC head + log_softmax ----
  head_kernel<<<N_GRAPHS, 64, 0, stream>>>(gU, fcW1, fcb1, fcW2, fcb2, out);
}